// Round 3
// baseline (418.019 us; speedup 1.0000x reference)
//
#include <hip/hip_runtime.h>

// Unfold (im2col): x[8,64,224,224] f32, 3x3 kernel, pad=1, stride=1, dil=1
// out[b, c*9 + k, oh*224 + ow] = x[b, c, oh+ki-1, ow+kj-1] (0 outside), k = ki*3+kj
// One thread per (b*c, 8-col segment): loads 3 rows x (2 aligned float4 + 2 edge
// scalars), composes the 3 kj-shifts in-register, 18 nontemporal float4 stores.

typedef float v4f __attribute__((ext_vector_type(4)));

constexpr int B = 8, C = 64, H = 224, W = 224;
constexpr int L  = H * W;          // 50176
constexpr int L4 = L / 4;          // 12544
constexpr int L8 = L / 8;          // 6272  (W % 8 == 0: segments never cross rows)
constexpr int CC = B * C;          // 512
constexpr unsigned TOTALT = (unsigned)CC * (unsigned)L8;  // 3,211,264 = 12544 * 256

__global__ __launch_bounds__(256) void unfold18_kernel(const float* __restrict__ x,
                                                       float* __restrict__ out) {
    unsigned t = blockIdx.x * 256u + threadIdx.x;   // TOTALT % 256 == 0: no tail
    unsigned l8 = t % (unsigned)L8;   // const-divisor -> magic mul
    unsigned cc = t / (unsigned)L8;
    int l  = (int)(l8 * 8u);
    int oh = l / W;
    int ow = l - oh * W;              // multiple of 8, 0..216

    const float* __restrict__ base = x + (size_t)cc * (size_t)L;

    v4f   q0[3], q1[3];
    float lft[3], rgt[3];
    #pragma unroll
    for (int ki = 0; ki < 3; ++ki) {
        int ih = oh + ki - 1;
        if (ih >= 0 && ih < H) {
            const float* __restrict__ src = base + ih * W;
            q0[ki] = *reinterpret_cast<const v4f*>(src + ow);       // aligned
            q1[ki] = *reinterpret_cast<const v4f*>(src + ow + 4);   // aligned
            lft[ki] = (ow > 0)     ? src[ow - 1] : 0.f;
            rgt[ki] = (ow < W - 8) ? src[ow + 8] : 0.f;
        } else {
            q0[ki] = (v4f)0.f; q1[ki] = (v4f)0.f;
            lft[ki] = 0.f;     rgt[ki] = 0.f;
        }
    }

    v4f* o = reinterpret_cast<v4f*>(out);
    size_t obase = (size_t)cc * 9u * (size_t)L4 + (size_t)(l8 * 2u);
    #pragma unroll
    for (int ki = 0; ki < 3; ++ki) {
        v4f a0 = { lft[ki],  q0[ki][0], q0[ki][1], q0[ki][2] };  // kj=0, cols ow-1..ow+2
        v4f a1 = { q0[ki][3], q1[ki][0], q1[ki][1], q1[ki][2] }; // kj=0, cols ow+3..ow+6
        v4f c0 = { q0[ki][1], q0[ki][2], q0[ki][3], q1[ki][0] }; // kj=2, cols ow+1..ow+4
        v4f c1 = { q1[ki][1], q1[ki][2], q1[ki][3], rgt[ki]  };  // kj=2, cols ow+5..ow+8
        size_t r0 = obase + (size_t)(ki * 3 + 0) * (size_t)L4;
        size_t r1 = obase + (size_t)(ki * 3 + 1) * (size_t)L4;
        size_t r2 = obase + (size_t)(ki * 3 + 2) * (size_t)L4;
        __builtin_nontemporal_store(a0,      o + r0);
        __builtin_nontemporal_store(a1,      o + r0 + 1);
        __builtin_nontemporal_store(q0[ki],  o + r1);
        __builtin_nontemporal_store(q1[ki],  o + r1 + 1);
        __builtin_nontemporal_store(c0,      o + r2);
        __builtin_nontemporal_store(c1,      o + r2 + 1);
    }
}

extern "C" void kernel_launch(void* const* d_in, const int* in_sizes, int n_in,
                              void* d_out, int out_size, void* d_ws, size_t ws_size,
                              hipStream_t stream) {
    const float* x = (const float*)d_in[0];
    float* out = (float*)d_out;
    unsigned blocks = TOTALT / 256u;  // 12,544
    unfold18_kernel<<<dim3(blocks), dim3(256), 0, stream>>>(x, out);
}

// Round 4
// 194.264 us; speedup vs baseline: 2.1518x; 2.1518x over previous
//
#include <hip/hip_runtime.h>

// Unfold (im2col): x[8,64,224,224] f32, 3x3 kernel, pad=1, stride=1, dil=1
// out[b, c*9 + k, oh*224 + ow] = x[b, c, oh+ki-1, ow+kj-1] (0 outside), k = ki*3+kj
// One thread per (b*c, 8-col segment): loads 3 rows x (2 aligned float4 + 2 edge
// scalars), composes the 3 kj-shifts in-register, 18 cached float4 stores.
// (R2 lesson: __builtin_nontemporal_store on this interleaved pattern caused
//  1.53x HBM write amplification — partial-line writes bypass L2 merging.)

typedef float v4f __attribute__((ext_vector_type(4)));

constexpr int B = 8, C = 64, H = 224, W = 224;
constexpr int L  = H * W;          // 50176
constexpr int L4 = L / 4;          // 12544
constexpr int L8 = L / 8;          // 6272  (W % 8 == 0: segments never cross rows)
constexpr int CC = B * C;          // 512
constexpr unsigned TOTALT = (unsigned)CC * (unsigned)L8;  // 3,211,264 = 12544 * 256

__global__ __launch_bounds__(256) void unfold18_kernel(const float* __restrict__ x,
                                                       float* __restrict__ out) {
    unsigned t = blockIdx.x * 256u + threadIdx.x;   // TOTALT % 256 == 0: no tail
    unsigned l8 = t % (unsigned)L8;   // const-divisor -> magic mul
    unsigned cc = t / (unsigned)L8;
    int l  = (int)(l8 * 8u);
    int oh = l / W;
    int ow = l - oh * W;              // multiple of 8, 0..216

    const float* __restrict__ base = x + (size_t)cc * (size_t)L;

    v4f   q0[3], q1[3];
    float lft[3], rgt[3];
    #pragma unroll
    for (int ki = 0; ki < 3; ++ki) {
        int ih = oh + ki - 1;
        if (ih >= 0 && ih < H) {
            const float* __restrict__ src = base + ih * W;
            q0[ki] = *reinterpret_cast<const v4f*>(src + ow);       // aligned
            q1[ki] = *reinterpret_cast<const v4f*>(src + ow + 4);   // aligned
            lft[ki] = (ow > 0)     ? src[ow - 1] : 0.f;
            rgt[ki] = (ow < W - 8) ? src[ow + 8] : 0.f;
        } else {
            q0[ki] = (v4f)0.f; q1[ki] = (v4f)0.f;
            lft[ki] = 0.f;     rgt[ki] = 0.f;
        }
    }

    v4f* __restrict__ o = reinterpret_cast<v4f*>(out);
    size_t obase = (size_t)cc * 9u * (size_t)L4 + (size_t)(l8 * 2u);
    #pragma unroll
    for (int ki = 0; ki < 3; ++ki) {
        v4f a0 = { lft[ki],  q0[ki][0], q0[ki][1], q0[ki][2] };  // kj=0, cols ow-1..ow+2
        v4f a1 = { q0[ki][3], q1[ki][0], q1[ki][1], q1[ki][2] }; // kj=0, cols ow+3..ow+6
        v4f c0 = { q0[ki][1], q0[ki][2], q0[ki][3], q1[ki][0] }; // kj=2, cols ow+1..ow+4
        v4f c1 = { q1[ki][1], q1[ki][2], q1[ki][3], rgt[ki]  };  // kj=2, cols ow+5..ow+8
        size_t r0 = obase + (size_t)(ki * 3 + 0) * (size_t)L4;
        size_t r1 = obase + (size_t)(ki * 3 + 1) * (size_t)L4;
        size_t r2 = obase + (size_t)(ki * 3 + 2) * (size_t)L4;
        o[r0]     = a0;
        o[r0 + 1] = a1;
        o[r1]     = q0[ki];
        o[r1 + 1] = q1[ki];
        o[r2]     = c0;
        o[r2 + 1] = c1;
    }
}

extern "C" void kernel_launch(void* const* d_in, const int* in_sizes, int n_in,
                              void* d_out, int out_size, void* d_ws, size_t ws_size,
                              hipStream_t stream) {
    const float* x = (const float*)d_in[0];
    float* out = (float*)d_out;
    unsigned blocks = TOTALT / 256u;  // 12,544
    unfold18_kernel<<<dim3(blocks), dim3(256), 0, stream>>>(x, out);
}